// Round 13
// baseline (229.885 us; speedup 1.0000x reference)
//
#include <hip/hip_runtime.h>
#include <stdint.h>
#include <cmath>

#define TOKENS 4096
#define HIDDEN 768
#define NHEADS 12
#define SEQ    1024
#define NBH    48   // B*NHEADS

typedef int   int32x4 __attribute__((ext_vector_type(4)));
typedef float f32x4   __attribute__((ext_vector_type(4)));
typedef short short8  __attribute__((ext_vector_type(8)));

struct PlaCoeffs { float m[12]; float c[12]; };

// ---------------- workspace layout (bytes) ----------------
#define WBYTES   ((size_t)HIDDEN * HIDDEN)
#define OFF_WQ    ((size_t)256)
#define OFF_WK    (OFF_WQ + WBYTES)
#define OFF_WV    (OFF_WK + WBYTES)
#define OFF_WO    (OFF_WV + WBYTES)
#define OFF_XQ1   (OFF_WO + WBYTES)
#define OFF_SC1   (OFF_XQ1 + (size_t)TOKENS * HIDDEN)
#define OFF_QH    (OFF_SC1 + (size_t)TOKENS * 4)
#define HB        ((size_t)NBH * SEQ * 64 * 2)
#define OFF_KH    (OFF_QH + HB)
#define OFF_VT    (OFF_KH + HB)
#define OFF_CTX   (OFF_VT + HB)
#define OFF_XQ2   (OFF_CTX + (size_t)TOKENS * HIDDEN * 4)
#define OFF_SC2   (OFF_XQ2 + (size_t)TOKENS * HIDDEN)

__device__ __forceinline__ unsigned short f2bf(float f) {
  unsigned int u = __float_as_uint(f);
  u = (u + 0x7fffu + ((u >> 16) & 1u)) >> 16;
  return (unsigned short)u;
}

// packed RTNE f32x2 -> bf16x2 (low = a, high = b); bit-identical to f2bf per element
__device__ __forceinline__ unsigned int cvtpk_bf16(float a, float b) {
  unsigned int r;
  asm volatile("v_cvt_pk_bf16_f32 %0, %1, %2" : "=v"(r) : "v"(a), "v"(b));
  return r;
}

// ---------------- PLA coefficients: host-side, replicates np.polyfit fit ----------------
static PlaCoeffs compute_pla_coeffs() {
  PlaCoeffs out;
  const double step_e = 10.0 / 12.0;
  for (int i = 0; i < 12; i++) {
    double e0 = (double)i * step_e + (-10.0);
    double e1 = (i + 1 == 12) ? 0.0 : (double)(i + 1) * step_e + (-10.0);
    double n = 0.0, Sx = 0.0, Sy = 0.0, Sxy = 0.0, Sxx = 0.0;
    for (int j = 0; j <= 1000; j++) {
      double x = (j == 1000) ? 0.0 : (double)j * 0.01 + (-10.0);  // == np.linspace(-10,0,1001)
      if (x >= e0 && x <= e1) {
        double y = std::exp(x);
        n += 1.0; Sx += x; Sy += y; Sxy += x * y; Sxx += x * x;
      }
    }
    double det = n * Sxx - Sx * Sx;
    double m = (n * Sxy - Sx * Sy) / det;
    double c = (Sy - m * Sx) / n;
    out.m[i] = (float)m;
    out.c[i] = (float)c;
  }
  return out;
}
static const PlaCoeffs g_pla = compute_pla_coeffs();

// ---------------- fused: per-token quant (blocks 0..4095) + weight pack (4096..6399) ----
__global__ void prep_kernel(const float* __restrict__ x, signed char* __restrict__ xq,
                            float* __restrict__ sc,
                            const int* __restrict__ w0, const int* __restrict__ w1,
                            const int* __restrict__ w2, const int* __restrict__ w3,
                            signed char* __restrict__ o0, signed char* __restrict__ o1,
                            signed char* __restrict__ o2, signed char* __restrict__ o3) {
  int tid = threadIdx.x;
  if (blockIdx.x < TOKENS) {
    int t = blockIdx.x;
    const float* row = x + (size_t)t * HIDDEN;
    float v0 = row[tid], v1 = row[tid + 256], v2 = row[tid + 512];
    float am = fmaxf(fabsf(v0), fmaxf(fabsf(v1), fabsf(v2)));
#pragma unroll
    for (int m = 1; m < 64; m <<= 1) am = fmaxf(am, __shfl_xor(am, m, 64));
    __shared__ float red[4];
    if ((tid & 63) == 0) red[tid >> 6] = am;
    __syncthreads();
    float total = fmaxf(fmaxf(red[0], red[1]), fmaxf(red[2], red[3]));
    float s = total / 127.0f;
    if (s == 0.0f) s = 1.0f;
    float q0 = fminf(fmaxf(rintf(v0 / s), -128.0f), 127.0f);
    float q1 = fminf(fmaxf(rintf(v1 / s), -128.0f), 127.0f);
    float q2 = fminf(fmaxf(rintf(v2 / s), -128.0f), 127.0f);
    signed char* orow = xq + (size_t)t * HIDDEN;
    orow[tid]       = (signed char)(int)q0;
    orow[tid + 256] = (signed char)(int)q1;
    orow[tid + 512] = (signed char)(int)q2;
    if (tid == 0) sc[t] = s;
  } else {
    int p = blockIdx.x - TOKENS;
    int z = p / 576, px = p % 576;
    const int* src = z == 0 ? w0 : z == 1 ? w1 : z == 2 ? w2 : w3;
    signed char* dst = z == 0 ? o0 : z == 1 ? o1 : z == 2 ? o2 : o3;
    int idx = (px * 256 + tid) * 4;
    int32x4 v = *(const int32x4*)(src + idx);
    int packed = (v[0] & 255) | ((v[1] & 255) << 8) | ((v[2] & 255) << 16) | (v[3] << 24);
    *(int*)(dst + idx) = packed;
  }
}

// ---------------- per-token dynamic int8 quantization (for ctx) ----------------
__global__ void quant_kernel(const float* __restrict__ x, signed char* __restrict__ xq,
                             float* __restrict__ sc) {
  int t = blockIdx.x;
  int tid = threadIdx.x;
  const float* row = x + (size_t)t * HIDDEN;
  float v0 = row[tid], v1 = row[tid + 256], v2 = row[tid + 512];
  float am = fmaxf(fabsf(v0), fmaxf(fabsf(v1), fabsf(v2)));
#pragma unroll
  for (int m = 1; m < 64; m <<= 1) am = fmaxf(am, __shfl_xor(am, m, 64));
  __shared__ float red[4];
  if ((tid & 63) == 0) red[tid >> 6] = am;
  __syncthreads();
  float total = fmaxf(fmaxf(red[0], red[1]), fmaxf(red[2], red[3]));
  float s = total / 127.0f;
  if (s == 0.0f) s = 1.0f;
  float q0 = fminf(fmaxf(rintf(v0 / s), -128.0f), 127.0f);
  float q1 = fminf(fmaxf(rintf(v1 / s), -128.0f), 127.0f);
  float q2 = fminf(fmaxf(rintf(v2 / s), -128.0f), 127.0f);
  signed char* orow = xq + (size_t)t * HIDDEN;
  orow[tid]       = (signed char)(int)q0;
  orow[tid + 256] = (signed char)(int)q1;
  orow[tid + 512] = (signed char)(int)q2;
  if (tid == 0) sc[t] = s;
}

// ---------------- shared int8 GEMM mainloop: 128x128 tile, BK=128, LDS dbuf ------------
__device__ __forceinline__ void i8_mainloop(const signed char* __restrict__ Abase,
                                            const signed char* __restrict__ Bbase,
                                            char* As, char* Bs, int tid,
                                            int32x4 acc[4][4]) {
  int lane = tid & 63, w = tid >> 6;
  int lr = lane & 15, lg = lane >> 4;
  int wr = w >> 1, wc = w & 1;
  int laneoff = (lane >> 3) * HIDDEN + (((lane & 7) ^ (lane >> 3)) * 16);
  int rowblk = w * 32;

#pragma unroll
  for (int ii = 0; ii < 4; ii++) {
    const signed char* sa = Abase + (size_t)(rowblk + ii * 8) * HIDDEN + laneoff;
    const signed char* sb = Bbase + (size_t)(rowblk + ii * 8) * HIDDEN + laneoff;
    __builtin_amdgcn_global_load_lds(
        (const __attribute__((address_space(1))) void*)sa,
        (__attribute__((address_space(3))) void*)(As + (w * 4 + ii) * 1024), 16, 0, 0);
    __builtin_amdgcn_global_load_lds(
        (const __attribute__((address_space(1))) void*)sb,
        (__attribute__((address_space(3))) void*)(Bs + (w * 4 + ii) * 1024), 16, 0, 0);
  }
  __syncthreads();

  int buf = 0;
  for (int ks = 0; ks < 6; ks++) {
    if (ks < 5) {
      char* An = As + (buf ^ 1) * 16384;
      char* Bn = Bs + (buf ^ 1) * 16384;
#pragma unroll
      for (int ii = 0; ii < 4; ii++) {
        const signed char* sa =
            Abase + (size_t)(rowblk + ii * 8) * HIDDEN + (ks + 1) * 128 + laneoff;
        const signed char* sb =
            Bbase + (size_t)(rowblk + ii * 8) * HIDDEN + (ks + 1) * 128 + laneoff;
        __builtin_amdgcn_global_load_lds(
            (const __attribute__((address_space(1))) void*)sa,
            (__attribute__((address_space(3))) void*)(An + (w * 4 + ii) * 1024), 16, 0, 0);
        __builtin_amdgcn_global_load_lds(
            (const __attribute__((address_space(1))) void*)sb,
            (__attribute__((address_space(3))) void*)(Bn + (w * 4 + ii) * 1024), 16, 0, 0);
      }
    }
    const char* Ac = As + buf * 16384;
    const char* Bc = Bs + buf * 16384;
#pragma unroll
    for (int ksub = 0; ksub < 2; ksub++) {
      int32x4 af[4], bf[4];
      int cs = (ksub * 4 + lg) ^ (lr & 7);
#pragma unroll
      for (int i = 0; i < 4; i++)
        af[i] = *(const int32x4*)(Ac + (wr * 64 + i * 16 + lr) * 128 + cs * 16);
#pragma unroll
      for (int j = 0; j < 4; j++)
        bf[j] = *(const int32x4*)(Bc + (wc * 64 + j * 16 + lr) * 128 + cs * 16);
#pragma unroll
      for (int i = 0; i < 4; i++)
#pragma unroll
        for (int j = 0; j < 4; j++)
          acc[i][j] = __builtin_amdgcn_mfma_i32_16x16x64_i8(af[i], bf[j], acc[i][j], 0, 0, 0);
    }
    __syncthreads();
    buf ^= 1;
  }
}

// ---------------- QKV int8 MFMA GEMM (M=4096,N=768,K=768) ----------------
__launch_bounds__(256, 2)
__global__ void qkv_gemm(const signed char* __restrict__ xq, const float* __restrict__ isc,
                         const signed char* __restrict__ wq, const signed char* __restrict__ wk,
                         const signed char* __restrict__ wv,
                         const float* __restrict__ wsq, const float* __restrict__ wsk,
                         const float* __restrict__ wsv,
                         const float* __restrict__ bq, const float* __restrict__ bk,
                         const float* __restrict__ bv,
                         unsigned short* __restrict__ qh, unsigned short* __restrict__ kh,
                         unsigned short* __restrict__ vt) {
  __shared__ __align__(16) char As[2 * 16384];
  __shared__ __align__(16) char Bs[2 * 16384];
  int z = blockIdx.z;
  const signed char* w   = z == 0 ? wq  : z == 1 ? wk  : wv;
  const float*       wsc = z == 0 ? wsq : z == 1 ? wsk : wsv;
  const float*       bias= z == 0 ? bq  : z == 1 ? bk  : bv;
  unsigned short*    out = z == 0 ? qh  : z == 1 ? kh  : vt;

  int tid = threadIdx.x;
  int lane = tid & 63, wave = tid >> 6;
  int lr = lane & 15, lg = lane >> 4;
  int mbase0 = blockIdx.x * 128;
  int mbase = mbase0 + (wave >> 1) * 64;
  int nbase = blockIdx.y * 128 + (wave & 1) * 64;

  int32x4 acc[4][4];
#pragma unroll
  for (int i = 0; i < 4; i++)
#pragma unroll
    for (int j = 0; j < 4; j++) acc[i][j] = (int32x4){0, 0, 0, 0};

  i8_mainloop(xq + (size_t)mbase0 * HIDDEN,
              w + (size_t)blockIdx.y * 128 * HIDDEN, As, Bs, tid, acc);

  if (z < 2) {
#pragma unroll
    for (int j = 0; j < 4; j++) {
      int col = nbase + j * 16 + lr;
      float wsv_ = wsc[col], bv_ = bias[col];
      int h = col >> 6, d = col & 63;
#pragma unroll
      for (int i = 0; i < 4; i++) {
#pragma unroll
        for (int r = 0; r < 4; r++) {
          int trow = mbase + i * 16 + lg * 4 + r;
          float v = (float)acc[i][j][r] * wsv_ * isc[trow] + bv_;
          int bb = trow >> 10, ss = trow & 1023;
          out[(((size_t)(bb * NHEADS + h)) * SEQ + ss) * 64 + d] = f2bf(v);
        }
      }
    }
  } else {
    // V^T: dequant -> bf16 -> swizzled LDS transpose -> coalesced 16B stores
    unsigned short* T = (unsigned short*)As;
#pragma unroll
    for (int j = 0; j < 4; j++) {
      int colc = (wave & 1) * 64 + j * 16 + lr;
      int gcol = blockIdx.y * 128 + colc;
      float wsv_ = wsc[gcol], bv_ = bias[gcol];
      int rlb = (wave >> 1) * 64 + lg * 4;
#pragma unroll
      for (int i = 0; i < 4; i++) {
        int rl = rlb + i * 16;
        float v0 = (float)acc[i][j][0] * wsv_ * isc[mbase0 + rl + 0] + bv_;
        float v1 = (float)acc[i][j][1] * wsv_ * isc[mbase0 + rl + 1] + bv_;
        float v2 = (float)acc[i][j][2] * wsv_ * isc[mbase0 + rl + 2] + bv_;
        float v3 = (float)acc[i][j][3] * wsv_ * isc[mbase0 + rl + 3] + bv_;
        int oct = (rl >> 3) ^ (colc & 7);
        unsigned short* dst = T + colc * 128 + (oct << 3) + (rl & 7);
        *(unsigned int*)(dst)     = cvtpk_bf16(v0, v1);
        *(unsigned int*)(dst + 2) = cvtpk_bf16(v2, v3);
      }
    }
    __syncthreads();
    int bb = mbase0 >> 10, ssb = mbase0 & 1023;
    int o = tid & 15, cb = (tid >> 4) * 8;
#pragma unroll
    for (int j = 0; j < 8; j++) {
      int colc = cb + j;
      int gcol = blockIdx.y * 128 + colc;
      int hh = gcol >> 6, dd = gcol & 63;
      unsigned short* g = out + (((size_t)(bb * NHEADS + hh)) * 64 + dd) * SEQ + ssb + o * 8;
      *(short8*)g = *(const short8*)(T + colc * 128 + ((o ^ (colc & 7)) << 3));
    }
  }
}

// ---------------- O-proj int8 MFMA GEMM -> fp32 d_out ----------------
__launch_bounds__(256, 2)
__global__ void o_gemm(const signed char* __restrict__ xq, const float* __restrict__ isc,
                       const signed char* __restrict__ w, const float* __restrict__ wsc,
                       const float* __restrict__ bias, float* __restrict__ out) {
  __shared__ __align__(16) char As[2 * 16384];
  __shared__ __align__(16) char Bs[2 * 16384];
  int tid = threadIdx.x;
  int lane = tid & 63, wave = tid >> 6;
  int lr = lane & 15, lg = lane >> 4;
  int mbase = blockIdx.x * 128 + (wave >> 1) * 64;
  int nbase = blockIdx.y * 128 + (wave & 1) * 64;

  int32x4 acc[4][4];
#pragma unroll
  for (int i = 0; i < 4; i++)
#pragma unroll
    for (int j = 0; j < 4; j++) acc[i][j] = (int32x4){0, 0, 0, 0};

  i8_mainloop(xq + (size_t)blockIdx.x * 128 * HIDDEN,
              w + (size_t)blockIdx.y * 128 * HIDDEN, As, Bs, tid, acc);

#pragma unroll
  for (int j = 0; j < 4; j++) {
    int col = nbase + j * 16 + lr;
    float wsv_ = wsc[col], bv_ = bias[col];
#pragma unroll
    for (int i = 0; i < 4; i++) {
#pragma unroll
      for (int r = 0; r < 4; r++) {
        int trow = mbase + i * 16 + lg * 4 + r;
        float v = (float)acc[i][j][r] * wsv_ * isc[trow] + bv_;
        out[(size_t)trow * HIDDEN + col] = v;
      }
    }
  }
}

// ---------------- attention: deferred PV + packed P dbuf (49152 B dynamic LDS) ---------
// R12's pipeline (PV[c-1] overlapped into chunk c, V in regs, P dbuf wave-private)
// with R10's proven 16x32 packed plds (swizzle col ^ ((row&3)<<3) ^ ((row>>2&1)<<4)).
// LDS = kbuf 16K + vbuf 16K + plds 16K = 48K (+2.2K statics) -> 2 blocks/CU like R8.
__launch_bounds__(512, 6)
__global__ void attn_kernel(const unsigned short* __restrict__ qh,
                            const unsigned short* __restrict__ kgl,
                            const unsigned short* __restrict__ vt,
                            const float* __restrict__ mask,
                            const PlaCoeffs cf,
                            float* __restrict__ ctx) {
  __shared__ __align__(16) char smem[49152];
  unsigned short* kbuf = (unsigned short*)smem;            // [2][4096] ushort (16 KB)
  unsigned short* vbuf = (unsigned short*)(smem + 16384);  // [2][4096] (16 KB)
  unsigned short* plds = (unsigned short*)(smem + 32768);  // [8 waves][2][512] (16 KB)
  float* parts = (float*)smem;                             // [8][16][64] post-loop alias
  __shared__ float rmaxp[8][16], rmaxv[4][16], rsump[8][16], rsumv[4][16];
  __shared__ float2 lmc[12];

  int tid = threadIdx.x;
  int lane = tid & 63, w = tid >> 6;
  int lr = lane & 15, lg = lane >> 4;
  int m = w & 3, kh2 = w >> 2;

  if (tid < 12) lmc[tid] = make_float2(cf.m[tid], cf.c[tid]);

  // bijective XCD swizzle: 768 = 8 XCD x 96; 6 whole heads per XCD
  int nb = (blockIdx.x & 7) * 96 + (blockIdx.x >> 3);
  int bh = nb >> 4, qt = nb & 15;
  int b = bh / NHEADS, h = bh % NHEADS;
  int qbase = qt * 64;

  const unsigned short* qp     = qh + ((size_t)bh * SEQ + qbase + m * 16) * 64;
  const unsigned short* khead  = kgl + (size_t)bh * SEQ * 64;
  const unsigned short* vthead = vt + (size_t)bh * 64 * SEQ;
  const float* mrow = mask + b * SEQ;

  short8 qa0 = *(const short8*)(qp + (size_t)lr * 64 + lg * 8);
  short8 qa1 = *(const short8*)(qp + (size_t)lr * 64 + 32 + lg * 8);

  int sr = tid >> 3, sd = (tid & 7) * 8;
  int sidx = sr * 64 + (sd ^ ((sr & 7) << 3));
  const unsigned short* kgp = khead + (size_t)sr * 64 + sd;    // + c*4096
  const unsigned short* vgp = vthead + (size_t)sr * 1024 + sd; // + c*64

  // ---- phase A: row max (K dbuf-staged, 1 barrier/chunk) ----
  float rm[4] = {-3.0e38f, -3.0e38f, -3.0e38f, -3.0e38f};
  short8 stk = *(const short8*)kgp;
  for (int c = 0; c < 16; c++) {
    unsigned short* kb = kbuf + (c & 1) * 4096;
    *(short8*)(kb + sidx) = stk;
    if (c < 15) stk = *(const short8*)(kgp + (size_t)(c + 1) * 4096);
    __syncthreads();
#pragma unroll
    for (int kt = 0; kt < 2; kt++) {
      int krow = kh2 * 32 + kt * 16 + lr;
      const unsigned short* kbp = kb + krow * 64;
      int sw = (krow & 7) << 3;
      short8 k0 = *(const short8*)(kbp + ((lg * 8) ^ sw));
      short8 k1 = *(const short8*)(kbp + ((32 + lg * 8) ^ sw));
      f32x4 a = {0.f, 0.f, 0.f, 0.f};
      __builtin_amdgcn_s_setprio(1);
      a = __builtin_amdgcn_mfma_f32_16x16x32_bf16(qa0, k0, a, 0, 0, 0);
      a = __builtin_amdgcn_mfma_f32_16x16x32_bf16(qa1, k1, a, 0, 0, 0);
      __builtin_amdgcn_s_setprio(0);
      float mk = mrow[c * 64 + krow];
#pragma unroll
      for (int r = 0; r < 4; r++) rm[r] = fmaxf(rm[r], fmaf(a[r], 0.125f, mk));
    }
  }
#pragma unroll
  for (int r = 0; r < 4; r++) {
#pragma unroll
    for (int msk = 1; msk < 16; msk <<= 1) rm[r] = fmaxf(rm[r], __shfl_xor(rm[r], msk, 64));
  }
  if (lr == 0) {
#pragma unroll
    for (int r = 0; r < 4; r++) rmaxp[w][lg * 4 + r] = rm[r];
  }
  __syncthreads();
  if (tid < 64) {
    int mm = tid >> 4, row = tid & 15;
    rmaxv[mm][row] = fmaxf(rmaxp[mm][row], rmaxp[mm + 4][row]);
  }
  __syncthreads();

  // ---- phase B: QK -> PLA -> P-write[c]; PV[c-1] deferred (reg-held V) ----
  float rmx[4], rs[4];
#pragma unroll
  for (int r = 0; r < 4; r++) { rmx[r] = rmaxv[m][lg * 4 + r]; rs[r] = 0.f; }
  f32x4 pacc[4];
#pragma unroll
  for (int n = 0; n < 4; n++) pacc[n] = (f32x4){0.f, 0.f, 0.f, 0.f};
  unsigned short* pw = plds + w * 1024;  // 2 slots x 512 ushorts (wave-private, packed)
  // packed 16x32 layout: element (row,c) at row*32 + (c ^ ((row&3)<<3) ^ ((row>>2&1)<<4))
  int paoff = lr * 32 + ((lg * 8) ^ ((lr & 3) << 3) ^ (((lr >> 2) & 1) << 4));

  short8 stk2 = *(const short8*)kgp;
  short8 stv  = *(const short8*)vgp;
  short8 vvA[4], vvB[4];

  auto chunk = [&](int c, short8* vprev, short8* vcur) {
    unsigned short* kb = kbuf + (c & 1) * 4096;
    unsigned short* vb = vbuf + (c & 1) * 4096;
    *(short8*)(kb + sidx) = stk2;
    *(short8*)(vb + sidx) = stv;
    if (c < 15) {
      stk2 = *(const short8*)(kgp + (size_t)(c + 1) * 4096);
      stv  = *(const short8*)(vgp + (c + 1) * 64);
    }
    __syncthreads();
    // V fragments for THIS chunk -> regs (consumed by PV next iteration)
#pragma unroll
    for (int n = 0; n < 4; n++) {
      int d = n * 16 + lr;
      vcur[n] = *(const short8*)(vb + d * 64 + ((kh2 * 32 + lg * 8) ^ ((d & 7) << 3)));
    }
    // pa for PREVIOUS chunk (own-wave plds, written last iteration -> no wait)
    short8 pa;
    if (c > 0) pa = *(const short8*)(pw + ((c - 1) & 1) * 512 + paoff);
    unsigned short* pw2 = pw + (c & 1) * 512;
#pragma unroll
    for (int kt = 0; kt < 2; kt++) {
      int krow = kh2 * 32 + kt * 16 + lr;
      const unsigned short* kbp = kb + krow * 64;
      int sw = (krow & 7) << 3;
      short8 k0 = *(const short8*)(kbp + ((lg * 8) ^ sw));
      short8 k1 = *(const short8*)(kbp + ((32 + lg * 8) ^ sw));
      f32x4 a = {0.f, 0.f, 0.f, 0.f};
      __builtin_amdgcn_s_setprio(1);
      a = __builtin_amdgcn_mfma_f32_16x16x32_bf16(qa0, k0, a, 0, 0, 0);
      a = __builtin_amdgcn_mfma_f32_16x16x32_bf16(qa1, k1, a, 0, 0, 0);
      // deferred PV for chunk c-1 overlaps the QK->PLA dependency gap
      if (kt == 0 && c > 0) {
#pragma unroll
        for (int n = 0; n < 4; n++)
          pacc[n] = __builtin_amdgcn_mfma_f32_16x16x32_bf16(pa, vprev[n], pacc[n], 0, 0, 0);
      }
      __builtin_amdgcn_s_setprio(0);
      float mk = mrow[c * 64 + krow];
      float p[4];
#pragma unroll
      for (int r = 0; r < 4; r++) {
        float x = fmaf(a[r], 0.125f, mk) - rmx[r];
        x = fminf(fmaxf(x, -10.f), 0.f);             // v_med3_f32
        int ii = (int)fmaf(x, 1.2f, 12.0f);
        ii = ii > 10 ? 10 : ii;
        float2 mc = lmc[ii];
        p[r] = fmaf(mc.x, x, mc.y);
        rs[r] += p[r];
      }
      unsigned int pk01 = cvtpk_bf16(p[0], p[1]);
      unsigned int pk23 = cvtpk_bf16(p[2], p[3]);
      int colw = kt * 16 + lr;
      int lgb = (lg & 1) << 4;
      pw2[(lg * 4 + 0) * 32 + (colw ^ 0  ^ lgb)] = (unsigned short)pk01;
      pw2[(lg * 4 + 1) * 32 + (colw ^ 8  ^ lgb)] = (unsigned short)(pk01 >> 16);
      pw2[(lg * 4 + 2) * 32 + (colw ^ 16 ^ lgb)] = (unsigned short)pk23;
      pw2[(lg * 4 + 3) * 32 + (colw ^ 24 ^ lgb)] = (unsigned short)(pk23 >> 16);
    }
  };

  for (int cc = 0; cc < 16; cc += 2) {
    chunk(cc, vvB, vvA);       // PV[cc-1] from vvB; V[cc] -> vvA
    chunk(cc + 1, vvA, vvB);   // PV[cc]   from vvA; V[cc+1] -> vvB
  }
  // final PV for chunk 15 (P in slot 15&1 = 1, V in vvB)
  {
    short8 pa = *(const short8*)(pw + 512 + paoff);
    __builtin_amdgcn_s_setprio(1);
#pragma unroll
    for (int n = 0; n < 4; n++)
      pacc[n] = __builtin_amdgcn_mfma_f32_16x16x32_bf16(pa, vvB[n], pacc[n], 0, 0, 0);
    __builtin_amdgcn_s_setprio(0);
  }

  // ---- tail: row sums + non-atomic PV combine (parts aliased over stage bufs) ----
#pragma unroll
  for (int r = 0; r < 4; r++) {
#pragma unroll
    for (int msk = 1; msk < 16; msk <<= 1) rs[r] += __shfl_xor(rs[r], msk, 64);
  }
  if (lr == 0) {
#pragma unroll
    for (int r = 0; r < 4; r++) rsump[w][lg * 4 + r] = rs[r];
  }
  __syncthreads();  // all phase-B LDS reads done; kbuf/vbuf/plds free, rsump visible
  {
    float* pslice = parts + w * 1024;  // [16][64]
#pragma unroll
    for (int n = 0; n < 4; n++)
#pragma unroll
      for (int r = 0; r < 4; r++)
        pslice[(lg * 4 + r) * 64 + n * 16 + lr] = pacc[n][r];
  }
  if (tid < 64) {
    int mm = tid >> 4, row = tid & 15;
    rsumv[mm][row] = rsump[mm][row] + rsump[mm + 4][row];
  }
  __syncthreads();

  // epilogue: out[mm*16+row][c8..c8+7] = (parts[mm] + parts[mm+4]) / denom
  {
    int mm = tid >> 7, row = (tid >> 3) & 15, c8 = (tid & 7) * 8;
    float dn = rsumv[mm][row] + 1e-9f;
    const float* p0 = parts + (mm * 16 + row) * 64 + c8;
    const float* p1 = p0 + 4 * 1024;
    f32x4 a0 = *(const f32x4*)p0, a1 = *(const f32x4*)(p0 + 4);
    f32x4 b0 = *(const f32x4*)p1, b1 = *(const f32x4*)(p1 + 4);
    f32x4 o0 = {(a0[0] + b0[0]) / dn, (a0[1] + b0[1]) / dn,
                (a0[2] + b0[2]) / dn, (a0[3] + b0[3]) / dn};
    f32x4 o1 = {(a1[0] + b1[0]) / dn, (a1[1] + b1[1]) / dn,
                (a1[2] + b1[2]) / dn, (a1[3] + b1[3]) / dn};
    float* op = &ctx[((size_t)b * SEQ + qbase + mm * 16 + row) * HIDDEN + h * 64 + c8];
    *(f32x4*)op = o0;
    *(f32x4*)(op + 4) = o1;
  }
}

// ---------------- launch ----------------
extern "C" void kernel_launch(void* const* d_in, const int* in_sizes, int n_in,
                              void* d_out, int out_size, void* d_ws, size_t ws_size,
                              hipStream_t stream) {
  const float* hidden = (const float*)d_in[0];
  const float* mask   = (const float*)d_in[1];
  const int*   wq  = (const int*)d_in[2];
  const float* wsq = (const float*)d_in[3];
  const float* bq  = (const float*)d_in[4];
  const int*   wk  = (const int*)d_in[5];
  const float* wsk = (const float*)d_in[6];
  const float* bk  = (const float*)d_in[7];
  const int*   wv  = (const int*)d_in[8];
  const float* wsv = (const float*)d_in[9];
  const float* bv  = (const float*)d_in[10];
  const int*   wo  = (const int*)d_in[11];
  const float* wso = (const float*)d_in[12];
  const float* bo  = (const float*)d_in[13];

  char* ws = (char*)d_ws;
  signed char*    pwq   = (signed char*)(ws + OFF_WQ);
  signed char*    pwk   = (signed char*)(ws + OFF_WK);
  signed char*    pwv   = (signed char*)(ws + OFF_WV);
  signed char*    pwo   = (signed char*)(ws + OFF_WO);
  signed char*    xq1   = (signed char*)(ws + OFF_XQ1);
  float*          sc1   = (float*)(ws + OFF_SC1);
  unsigned short* qhp   = (unsigned short*)(ws + OFF_QH);
  unsigned short* khp   = (unsigned short*)(ws + OFF_KH);
  unsigned short* vtp   = (unsigned short*)(ws + OFF_VT);
  float*          ctxp  = (float*)(ws + OFF_CTX);
  signed char*    xq2   = (signed char*)(ws + OFF_XQ2);
  float*          sc2   = (float*)(ws + OFF_SC2);

  prep_kernel<<<TOKENS + 2304, 256, 0, stream>>>(hidden, xq1, sc1,
                                                 wq, wk, wv, wo, pwq, pwk, pwv, pwo);
  qkv_gemm<<<dim3(32, 6, 3), 256, 0, stream>>>(xq1, sc1, pwq, pwk, pwv,
                                               wsq, wsk, wsv, bq, bk, bv,
                                               qhp, khp, vtp);
  attn_kernel<<<768, 512, 0, stream>>>(qhp, khp, vtp, mask, g_pla, ctxp);
  quant_kernel<<<TOKENS, 256, 0, stream>>>(ctxp, xq2, sc2);
  o_gemm<<<dim3(32, 6, 1), 256, 0, stream>>>(xq2, sc2, pwo, wso, bo, (float*)d_out);
}

// Round 14
// 96.604 us; speedup vs baseline: 2.3797x; 2.3797x over previous
//
#include <hip/hip_runtime.h>
#include <stdint.h>
#include <cmath>

#define TOKENS 4096
#define HIDDEN 768
#define NHEADS 12
#define SEQ    1024
#define NBH    48   // B*NHEADS

typedef int   int32x4 __attribute__((ext_vector_type(4)));
typedef float f32x4   __attribute__((ext_vector_type(4)));
typedef short short8  __attribute__((ext_vector_type(8)));

struct PlaCoeffs { float m[12]; float c[12]; };

// ---------------- workspace layout (bytes) ----------------
#define WBYTES   ((size_t)HIDDEN * HIDDEN)
#define OFF_WQ    ((size_t)256)
#define OFF_WK    (OFF_WQ + WBYTES)
#define OFF_WV    (OFF_WK + WBYTES)
#define OFF_WO    (OFF_WV + WBYTES)
#define OFF_XQ1   (OFF_WO + WBYTES)
#define OFF_SC1   (OFF_XQ1 + (size_t)TOKENS * HIDDEN)
#define OFF_QH    (OFF_SC1 + (size_t)TOKENS * 4)
#define HB        ((size_t)NBH * SEQ * 64 * 2)
#define OFF_KH    (OFF_QH + HB)
#define OFF_VT    (OFF_KH + HB)
#define OFF_CTX   (OFF_VT + HB)
#define OFF_XQ2   (OFF_CTX + (size_t)TOKENS * HIDDEN * 4)
#define OFF_SC2   (OFF_XQ2 + (size_t)TOKENS * HIDDEN)

__device__ __forceinline__ unsigned short f2bf(float f) {
  unsigned int u = __float_as_uint(f);
  u = (u + 0x7fffu + ((u >> 16) & 1u)) >> 16;
  return (unsigned short)u;
}

// packed RTNE f32x2 -> bf16x2 (low = a, high = b); bit-identical to f2bf per element
__device__ __forceinline__ unsigned int cvtpk_bf16(float a, float b) {
  unsigned int r;
  asm volatile("v_cvt_pk_bf16_f32 %0, %1, %2" : "=v"(r) : "v"(a), "v"(b));
  return r;
}

// ---------------- PLA coefficients: host-side, replicates np.polyfit fit ----------------
static PlaCoeffs compute_pla_coeffs() {
  PlaCoeffs out;
  const double step_e = 10.0 / 12.0;
  for (int i = 0; i < 12; i++) {
    double e0 = (double)i * step_e + (-10.0);
    double e1 = (i + 1 == 12) ? 0.0 : (double)(i + 1) * step_e + (-10.0);
    double n = 0.0, Sx = 0.0, Sy = 0.0, Sxy = 0.0, Sxx = 0.0;
    for (int j = 0; j <= 1000; j++) {
      double x = (j == 1000) ? 0.0 : (double)j * 0.01 + (-10.0);  // == np.linspace(-10,0,1001)
      if (x >= e0 && x <= e1) {
        double y = std::exp(x);
        n += 1.0; Sx += x; Sy += y; Sxy += x * y; Sxx += x * x;
      }
    }
    double det = n * Sxx - Sx * Sx;
    double m = (n * Sxy - Sx * Sy) / det;
    double c = (Sy - m * Sx) / n;
    out.m[i] = (float)m;
    out.c[i] = (float)c;
  }
  return out;
}
static const PlaCoeffs g_pla = compute_pla_coeffs();

// ---------------- fused: per-token quant (blocks 0..4095) + weight pack (4096..6399) ----
__global__ void prep_kernel(const float* __restrict__ x, signed char* __restrict__ xq,
                            float* __restrict__ sc,
                            const int* __restrict__ w0, const int* __restrict__ w1,
                            const int* __restrict__ w2, const int* __restrict__ w3,
                            signed char* __restrict__ o0, signed char* __restrict__ o1,
                            signed char* __restrict__ o2, signed char* __restrict__ o3) {
  int tid = threadIdx.x;
  if (blockIdx.x < TOKENS) {
    int t = blockIdx.x;
    const float* row = x + (size_t)t * HIDDEN;
    float v0 = row[tid], v1 = row[tid + 256], v2 = row[tid + 512];
    float am = fmaxf(fabsf(v0), fmaxf(fabsf(v1), fabsf(v2)));
#pragma unroll
    for (int m = 1; m < 64; m <<= 1) am = fmaxf(am, __shfl_xor(am, m, 64));
    __shared__ float red[4];
    if ((tid & 63) == 0) red[tid >> 6] = am;
    __syncthreads();
    float total = fmaxf(fmaxf(red[0], red[1]), fmaxf(red[2], red[3]));
    float s = total / 127.0f;
    if (s == 0.0f) s = 1.0f;
    float q0 = fminf(fmaxf(rintf(v0 / s), -128.0f), 127.0f);
    float q1 = fminf(fmaxf(rintf(v1 / s), -128.0f), 127.0f);
    float q2 = fminf(fmaxf(rintf(v2 / s), -128.0f), 127.0f);
    signed char* orow = xq + (size_t)t * HIDDEN;
    orow[tid]       = (signed char)(int)q0;
    orow[tid + 256] = (signed char)(int)q1;
    orow[tid + 512] = (signed char)(int)q2;
    if (tid == 0) sc[t] = s;
  } else {
    int p = blockIdx.x - TOKENS;
    int z = p / 576, px = p % 576;
    const int* src = z == 0 ? w0 : z == 1 ? w1 : z == 2 ? w2 : w3;
    signed char* dst = z == 0 ? o0 : z == 1 ? o1 : z == 2 ? o2 : o3;
    int idx = (px * 256 + tid) * 4;
    int32x4 v = *(const int32x4*)(src + idx);
    int packed = (v[0] & 255) | ((v[1] & 255) << 8) | ((v[2] & 255) << 16) | (v[3] << 24);
    *(int*)(dst + idx) = packed;
  }
}

// ---------------- per-token dynamic int8 quantization (for ctx) ----------------
__global__ void quant_kernel(const float* __restrict__ x, signed char* __restrict__ xq,
                             float* __restrict__ sc) {
  int t = blockIdx.x;
  int tid = threadIdx.x;
  const float* row = x + (size_t)t * HIDDEN;
  float v0 = row[tid], v1 = row[tid + 256], v2 = row[tid + 512];
  float am = fmaxf(fabsf(v0), fmaxf(fabsf(v1), fabsf(v2)));
#pragma unroll
  for (int m = 1; m < 64; m <<= 1) am = fmaxf(am, __shfl_xor(am, m, 64));
  __shared__ float red[4];
  if ((tid & 63) == 0) red[tid >> 6] = am;
  __syncthreads();
  float total = fmaxf(fmaxf(red[0], red[1]), fmaxf(red[2], red[3]));
  float s = total / 127.0f;
  if (s == 0.0f) s = 1.0f;
  float q0 = fminf(fmaxf(rintf(v0 / s), -128.0f), 127.0f);
  float q1 = fminf(fmaxf(rintf(v1 / s), -128.0f), 127.0f);
  float q2 = fminf(fmaxf(rintf(v2 / s), -128.0f), 127.0f);
  signed char* orow = xq + (size_t)t * HIDDEN;
  orow[tid]       = (signed char)(int)q0;
  orow[tid + 256] = (signed char)(int)q1;
  orow[tid + 512] = (signed char)(int)q2;
  if (tid == 0) sc[t] = s;
}

// ---------------- shared int8 GEMM mainloop: 128x128 tile, BK=128, LDS dbuf ------------
__device__ __forceinline__ void i8_mainloop(const signed char* __restrict__ Abase,
                                            const signed char* __restrict__ Bbase,
                                            char* As, char* Bs, int tid,
                                            int32x4 acc[4][4]) {
  int lane = tid & 63, w = tid >> 6;
  int lr = lane & 15, lg = lane >> 4;
  int wr = w >> 1, wc = w & 1;
  int laneoff = (lane >> 3) * HIDDEN + (((lane & 7) ^ (lane >> 3)) * 16);
  int rowblk = w * 32;

#pragma unroll
  for (int ii = 0; ii < 4; ii++) {
    const signed char* sa = Abase + (size_t)(rowblk + ii * 8) * HIDDEN + laneoff;
    const signed char* sb = Bbase + (size_t)(rowblk + ii * 8) * HIDDEN + laneoff;
    __builtin_amdgcn_global_load_lds(
        (const __attribute__((address_space(1))) void*)sa,
        (__attribute__((address_space(3))) void*)(As + (w * 4 + ii) * 1024), 16, 0, 0);
    __builtin_amdgcn_global_load_lds(
        (const __attribute__((address_space(1))) void*)sb,
        (__attribute__((address_space(3))) void*)(Bs + (w * 4 + ii) * 1024), 16, 0, 0);
  }
  __syncthreads();

  int buf = 0;
  for (int ks = 0; ks < 6; ks++) {
    if (ks < 5) {
      char* An = As + (buf ^ 1) * 16384;
      char* Bn = Bs + (buf ^ 1) * 16384;
#pragma unroll
      for (int ii = 0; ii < 4; ii++) {
        const signed char* sa =
            Abase + (size_t)(rowblk + ii * 8) * HIDDEN + (ks + 1) * 128 + laneoff;
        const signed char* sb =
            Bbase + (size_t)(rowblk + ii * 8) * HIDDEN + (ks + 1) * 128 + laneoff;
        __builtin_amdgcn_global_load_lds(
            (const __attribute__((address_space(1))) void*)sa,
            (__attribute__((address_space(3))) void*)(An + (w * 4 + ii) * 1024), 16, 0, 0);
        __builtin_amdgcn_global_load_lds(
            (const __attribute__((address_space(1))) void*)sb,
            (__attribute__((address_space(3))) void*)(Bn + (w * 4 + ii) * 1024), 16, 0, 0);
      }
    }
    const char* Ac = As + buf * 16384;
    const char* Bc = Bs + buf * 16384;
#pragma unroll
    for (int ksub = 0; ksub < 2; ksub++) {
      int32x4 af[4], bf[4];
      int cs = (ksub * 4 + lg) ^ (lr & 7);
#pragma unroll
      for (int i = 0; i < 4; i++)
        af[i] = *(const int32x4*)(Ac + (wr * 64 + i * 16 + lr) * 128 + cs * 16);
#pragma unroll
      for (int j = 0; j < 4; j++)
        bf[j] = *(const int32x4*)(Bc + (wc * 64 + j * 16 + lr) * 128 + cs * 16);
#pragma unroll
      for (int i = 0; i < 4; i++)
#pragma unroll
        for (int j = 0; j < 4; j++)
          acc[i][j] = __builtin_amdgcn_mfma_i32_16x16x64_i8(af[i], bf[j], acc[i][j], 0, 0, 0);
    }
    __syncthreads();
    buf ^= 1;
  }
}

// ---------------- QKV int8 MFMA GEMM (M=4096,N=768,K=768) ----------------
__launch_bounds__(256, 2)
__global__ void qkv_gemm(const signed char* __restrict__ xq, const float* __restrict__ isc,
                         const signed char* __restrict__ wq, const signed char* __restrict__ wk,
                         const signed char* __restrict__ wv,
                         const float* __restrict__ wsq, const float* __restrict__ wsk,
                         const float* __restrict__ wsv,
                         const float* __restrict__ bq, const float* __restrict__ bk,
                         const float* __restrict__ bv,
                         unsigned short* __restrict__ qh, unsigned short* __restrict__ kh,
                         unsigned short* __restrict__ vt) {
  __shared__ __align__(16) char As[2 * 16384];
  __shared__ __align__(16) char Bs[2 * 16384];
  int z = blockIdx.z;
  const signed char* w   = z == 0 ? wq  : z == 1 ? wk  : wv;
  const float*       wsc = z == 0 ? wsq : z == 1 ? wsk : wsv;
  const float*       bias= z == 0 ? bq  : z == 1 ? bk  : bv;
  unsigned short*    out = z == 0 ? qh  : z == 1 ? kh  : vt;

  int tid = threadIdx.x;
  int lane = tid & 63, wave = tid >> 6;
  int lr = lane & 15, lg = lane >> 4;
  int mbase0 = blockIdx.x * 128;
  int mbase = mbase0 + (wave >> 1) * 64;
  int nbase = blockIdx.y * 128 + (wave & 1) * 64;

  int32x4 acc[4][4];
#pragma unroll
  for (int i = 0; i < 4; i++)
#pragma unroll
    for (int j = 0; j < 4; j++) acc[i][j] = (int32x4){0, 0, 0, 0};

  i8_mainloop(xq + (size_t)mbase0 * HIDDEN,
              w + (size_t)blockIdx.y * 128 * HIDDEN, As, Bs, tid, acc);

  if (z < 2) {
#pragma unroll
    for (int j = 0; j < 4; j++) {
      int col = nbase + j * 16 + lr;
      float wsv_ = wsc[col], bv_ = bias[col];
      int h = col >> 6, d = col & 63;
#pragma unroll
      for (int i = 0; i < 4; i++) {
#pragma unroll
        for (int r = 0; r < 4; r++) {
          int trow = mbase + i * 16 + lg * 4 + r;
          float v = (float)acc[i][j][r] * wsv_ * isc[trow] + bv_;
          int bb = trow >> 10, ss = trow & 1023;
          out[(((size_t)(bb * NHEADS + h)) * SEQ + ss) * 64 + d] = f2bf(v);
        }
      }
    }
  } else {
    // V^T: dequant -> bf16 -> swizzled LDS transpose -> coalesced 16B stores
    unsigned short* T = (unsigned short*)As;
#pragma unroll
    for (int j = 0; j < 4; j++) {
      int colc = (wave & 1) * 64 + j * 16 + lr;
      int gcol = blockIdx.y * 128 + colc;
      float wsv_ = wsc[gcol], bv_ = bias[gcol];
      int rlb = (wave >> 1) * 64 + lg * 4;
#pragma unroll
      for (int i = 0; i < 4; i++) {
        int rl = rlb + i * 16;
        float v0 = (float)acc[i][j][0] * wsv_ * isc[mbase0 + rl + 0] + bv_;
        float v1 = (float)acc[i][j][1] * wsv_ * isc[mbase0 + rl + 1] + bv_;
        float v2 = (float)acc[i][j][2] * wsv_ * isc[mbase0 + rl + 2] + bv_;
        float v3 = (float)acc[i][j][3] * wsv_ * isc[mbase0 + rl + 3] + bv_;
        int oct = (rl >> 3) ^ (colc & 7);
        unsigned short* dst = T + colc * 128 + (oct << 3) + (rl & 7);
        *(unsigned int*)(dst)     = cvtpk_bf16(v0, v1);
        *(unsigned int*)(dst + 2) = cvtpk_bf16(v2, v3);
      }
    }
    __syncthreads();
    int bb = mbase0 >> 10, ssb = mbase0 & 1023;
    int o = tid & 15, cb = (tid >> 4) * 8;
#pragma unroll
    for (int j = 0; j < 8; j++) {
      int colc = cb + j;
      int gcol = blockIdx.y * 128 + colc;
      int hh = gcol >> 6, dd = gcol & 63;
      unsigned short* g = out + (((size_t)(bb * NHEADS + hh)) * 64 + dd) * SEQ + ssb + o * 8;
      *(short8*)g = *(const short8*)(T + colc * 128 + ((o ^ (colc & 7)) << 3));
    }
  }
}

// ---------------- O-proj int8 MFMA GEMM -> fp32 d_out ----------------
__launch_bounds__(256, 2)
__global__ void o_gemm(const signed char* __restrict__ xq, const float* __restrict__ isc,
                       const signed char* __restrict__ w, const float* __restrict__ wsc,
                       const float* __restrict__ bias, float* __restrict__ out) {
  __shared__ __align__(16) char As[2 * 16384];
  __shared__ __align__(16) char Bs[2 * 16384];
  int tid = threadIdx.x;
  int lane = tid & 63, wave = tid >> 6;
  int lr = lane & 15, lg = lane >> 4;
  int mbase = blockIdx.x * 128 + (wave >> 1) * 64;
  int nbase = blockIdx.y * 128 + (wave & 1) * 64;

  int32x4 acc[4][4];
#pragma unroll
  for (int i = 0; i < 4; i++)
#pragma unroll
    for (int j = 0; j < 4; j++) acc[i][j] = (int32x4){0, 0, 0, 0};

  i8_mainloop(xq + (size_t)blockIdx.x * 128 * HIDDEN,
              w + (size_t)blockIdx.y * 128 * HIDDEN, As, Bs, tid, acc);

#pragma unroll
  for (int j = 0; j < 4; j++) {
    int col = nbase + j * 16 + lr;
    float wsv_ = wsc[col], bv_ = bias[col];
#pragma unroll
    for (int i = 0; i < 4; i++) {
#pragma unroll
      for (int r = 0; r < 4; r++) {
        int trow = mbase + i * 16 + lg * 4 + r;
        float v = (float)acc[i][j][r] * wsv_ * isc[trow] + bv_;
        out[(size_t)trow * HIDDEN + col] = v;
      }
    }
  }
}

// ---------------- attention: deferred PV + packed P dbuf, 49152 B LDS, (512,4) ---------
// Identical to R13 except __launch_bounds__(512,4): R13's (512,6) capped VGPR at ~84 and
// spilled the deferred-PV pipeline to scratch (FETCH 404 MB). (512,4) gives the 128-reg
// budget R12 ran at (64 VGPR, no spill) while the 48K+statics LDS keeps 2 blocks/CU.
__launch_bounds__(512, 4)
__global__ void attn_kernel(const unsigned short* __restrict__ qh,
                            const unsigned short* __restrict__ kgl,
                            const unsigned short* __restrict__ vt,
                            const float* __restrict__ mask,
                            const PlaCoeffs cf,
                            float* __restrict__ ctx) {
  __shared__ __align__(16) char smem[49152];
  unsigned short* kbuf = (unsigned short*)smem;            // [2][4096] ushort (16 KB)
  unsigned short* vbuf = (unsigned short*)(smem + 16384);  // [2][4096] (16 KB)
  unsigned short* plds = (unsigned short*)(smem + 32768);  // [8 waves][2][512] (16 KB)
  float* parts = (float*)smem;                             // [8][16][64] post-loop alias
  __shared__ float rmaxp[8][16], rmaxv[4][16], rsump[8][16], rsumv[4][16];
  __shared__ float2 lmc[12];

  int tid = threadIdx.x;
  int lane = tid & 63, w = tid >> 6;
  int lr = lane & 15, lg = lane >> 4;
  int m = w & 3, kh2 = w >> 2;

  if (tid < 12) lmc[tid] = make_float2(cf.m[tid], cf.c[tid]);

  // bijective XCD swizzle: 768 = 8 XCD x 96; 6 whole heads per XCD
  int nb = (blockIdx.x & 7) * 96 + (blockIdx.x >> 3);
  int bh = nb >> 4, qt = nb & 15;
  int b = bh / NHEADS, h = bh % NHEADS;
  int qbase = qt * 64;

  const unsigned short* qp     = qh + ((size_t)bh * SEQ + qbase + m * 16) * 64;
  const unsigned short* khead  = kgl + (size_t)bh * SEQ * 64;
  const unsigned short* vthead = vt + (size_t)bh * 64 * SEQ;
  const float* mrow = mask + b * SEQ;

  short8 qa0 = *(const short8*)(qp + (size_t)lr * 64 + lg * 8);
  short8 qa1 = *(const short8*)(qp + (size_t)lr * 64 + 32 + lg * 8);

  int sr = tid >> 3, sd = (tid & 7) * 8;
  int sidx = sr * 64 + (sd ^ ((sr & 7) << 3));
  const unsigned short* kgp = khead + (size_t)sr * 64 + sd;    // + c*4096
  const unsigned short* vgp = vthead + (size_t)sr * 1024 + sd; // + c*64

  // ---- phase A: row max (K dbuf-staged, 1 barrier/chunk) ----
  float rm[4] = {-3.0e38f, -3.0e38f, -3.0e38f, -3.0e38f};
  short8 stk = *(const short8*)kgp;
  for (int c = 0; c < 16; c++) {
    unsigned short* kb = kbuf + (c & 1) * 4096;
    *(short8*)(kb + sidx) = stk;
    if (c < 15) stk = *(const short8*)(kgp + (size_t)(c + 1) * 4096);
    __syncthreads();
#pragma unroll
    for (int kt = 0; kt < 2; kt++) {
      int krow = kh2 * 32 + kt * 16 + lr;
      const unsigned short* kbp = kb + krow * 64;
      int sw = (krow & 7) << 3;
      short8 k0 = *(const short8*)(kbp + ((lg * 8) ^ sw));
      short8 k1 = *(const short8*)(kbp + ((32 + lg * 8) ^ sw));
      f32x4 a = {0.f, 0.f, 0.f, 0.f};
      __builtin_amdgcn_s_setprio(1);
      a = __builtin_amdgcn_mfma_f32_16x16x32_bf16(qa0, k0, a, 0, 0, 0);
      a = __builtin_amdgcn_mfma_f32_16x16x32_bf16(qa1, k1, a, 0, 0, 0);
      __builtin_amdgcn_s_setprio(0);
      float mk = mrow[c * 64 + krow];
#pragma unroll
      for (int r = 0; r < 4; r++) rm[r] = fmaxf(rm[r], fmaf(a[r], 0.125f, mk));
    }
  }
#pragma unroll
  for (int r = 0; r < 4; r++) {
#pragma unroll
    for (int msk = 1; msk < 16; msk <<= 1) rm[r] = fmaxf(rm[r], __shfl_xor(rm[r], msk, 64));
  }
  if (lr == 0) {
#pragma unroll
    for (int r = 0; r < 4; r++) rmaxp[w][lg * 4 + r] = rm[r];
  }
  __syncthreads();
  if (tid < 64) {
    int mm = tid >> 4, row = tid & 15;
    rmaxv[mm][row] = fmaxf(rmaxp[mm][row], rmaxp[mm + 4][row]);
  }
  __syncthreads();

  // ---- phase B: QK -> PLA -> P-write[c]; PV[c-1] deferred (reg-held V) ----
  float rmx[4], rs[4];
#pragma unroll
  for (int r = 0; r < 4; r++) { rmx[r] = rmaxv[m][lg * 4 + r]; rs[r] = 0.f; }
  f32x4 pacc[4];
#pragma unroll
  for (int n = 0; n < 4; n++) pacc[n] = (f32x4){0.f, 0.f, 0.f, 0.f};
  unsigned short* pw = plds + w * 1024;  // 2 slots x 512 ushorts (wave-private, packed)
  // packed 16x32 layout: element (row,c) at row*32 + (c ^ ((row&3)<<3) ^ ((row>>2&1)<<4))
  int paoff = lr * 32 + ((lg * 8) ^ ((lr & 3) << 3) ^ (((lr >> 2) & 1) << 4));

  short8 stk2 = *(const short8*)kgp;
  short8 stv  = *(const short8*)vgp;
  short8 vvA[4], vvB[4];

  auto chunk = [&](int c, short8* vprev, short8* vcur) {
    unsigned short* kb = kbuf + (c & 1) * 4096;
    unsigned short* vb = vbuf + (c & 1) * 4096;
    *(short8*)(kb + sidx) = stk2;
    *(short8*)(vb + sidx) = stv;
    if (c < 15) {
      stk2 = *(const short8*)(kgp + (size_t)(c + 1) * 4096);
      stv  = *(const short8*)(vgp + (c + 1) * 64);
    }
    __syncthreads();
    // V fragments for THIS chunk -> regs (consumed by PV next iteration)
#pragma unroll
    for (int n = 0; n < 4; n++) {
      int d = n * 16 + lr;
      vcur[n] = *(const short8*)(vb + d * 64 + ((kh2 * 32 + lg * 8) ^ ((d & 7) << 3)));
    }
    // pa for PREVIOUS chunk (own-wave plds, written last iteration -> no wait)
    short8 pa;
    if (c > 0) pa = *(const short8*)(pw + ((c - 1) & 1) * 512 + paoff);
    unsigned short* pw2 = pw + (c & 1) * 512;
#pragma unroll
    for (int kt = 0; kt < 2; kt++) {
      int krow = kh2 * 32 + kt * 16 + lr;
      const unsigned short* kbp = kb + krow * 64;
      int sw = (krow & 7) << 3;
      short8 k0 = *(const short8*)(kbp + ((lg * 8) ^ sw));
      short8 k1 = *(const short8*)(kbp + ((32 + lg * 8) ^ sw));
      f32x4 a = {0.f, 0.f, 0.f, 0.f};
      __builtin_amdgcn_s_setprio(1);
      a = __builtin_amdgcn_mfma_f32_16x16x32_bf16(qa0, k0, a, 0, 0, 0);
      a = __builtin_amdgcn_mfma_f32_16x16x32_bf16(qa1, k1, a, 0, 0, 0);
      // deferred PV for chunk c-1 overlaps the QK->PLA dependency gap
      if (kt == 0 && c > 0) {
#pragma unroll
        for (int n = 0; n < 4; n++)
          pacc[n] = __builtin_amdgcn_mfma_f32_16x16x32_bf16(pa, vprev[n], pacc[n], 0, 0, 0);
      }
      __builtin_amdgcn_s_setprio(0);
      float mk = mrow[c * 64 + krow];
      float p[4];
#pragma unroll
      for (int r = 0; r < 4; r++) {
        float x = fmaf(a[r], 0.125f, mk) - rmx[r];
        x = fminf(fmaxf(x, -10.f), 0.f);             // v_med3_f32
        int ii = (int)fmaf(x, 1.2f, 12.0f);
        ii = ii > 10 ? 10 : ii;
        float2 mc = lmc[ii];
        p[r] = fmaf(mc.x, x, mc.y);
        rs[r] += p[r];
      }
      unsigned int pk01 = cvtpk_bf16(p[0], p[1]);
      unsigned int pk23 = cvtpk_bf16(p[2], p[3]);
      int colw = kt * 16 + lr;
      int lgb = (lg & 1) << 4;
      pw2[(lg * 4 + 0) * 32 + (colw ^ 0  ^ lgb)] = (unsigned short)pk01;
      pw2[(lg * 4 + 1) * 32 + (colw ^ 8  ^ lgb)] = (unsigned short)(pk01 >> 16);
      pw2[(lg * 4 + 2) * 32 + (colw ^ 16 ^ lgb)] = (unsigned short)pk23;
      pw2[(lg * 4 + 3) * 32 + (colw ^ 24 ^ lgb)] = (unsigned short)(pk23 >> 16);
    }
  };

  for (int cc = 0; cc < 16; cc += 2) {
    chunk(cc, vvB, vvA);       // PV[cc-1] from vvB; V[cc] -> vvA
    chunk(cc + 1, vvA, vvB);   // PV[cc]   from vvA; V[cc+1] -> vvB
  }
  // final PV for chunk 15 (P in slot 15&1 = 1, V in vvB)
  {
    short8 pa = *(const short8*)(pw + 512 + paoff);
    __builtin_amdgcn_s_setprio(1);
#pragma unroll
    for (int n = 0; n < 4; n++)
      pacc[n] = __builtin_amdgcn_mfma_f32_16x16x32_bf16(pa, vvB[n], pacc[n], 0, 0, 0);
    __builtin_amdgcn_s_setprio(0);
  }

  // ---- tail: row sums + non-atomic PV combine (parts aliased over stage bufs) ----
#pragma unroll
  for (int r = 0; r < 4; r++) {
#pragma unroll
    for (int msk = 1; msk < 16; msk <<= 1) rs[r] += __shfl_xor(rs[r], msk, 64);
  }
  if (lr == 0) {
#pragma unroll
    for (int r = 0; r < 4; r++) rsump[w][lg * 4 + r] = rs[r];
  }
  __syncthreads();  // all phase-B LDS reads done; kbuf/vbuf/plds free, rsump visible
  {
    float* pslice = parts + w * 1024;  // [16][64]
#pragma unroll
    for (int n = 0; n < 4; n++)
#pragma unroll
      for (int r = 0; r < 4; r++)
        pslice[(lg * 4 + r) * 64 + n * 16 + lr] = pacc[n][r];
  }
  if (tid < 64) {
    int mm = tid >> 4, row = tid & 15;
    rsumv[mm][row] = rsump[mm][row] + rsump[mm + 4][row];
  }
  __syncthreads();

  // epilogue: out[mm*16+row][c8..c8+7] = (parts[mm] + parts[mm+4]) / denom
  {
    int mm = tid >> 7, row = (tid >> 3) & 15, c8 = (tid & 7) * 8;
    float dn = rsumv[mm][row] + 1e-9f;
    const float* p0 = parts + (mm * 16 + row) * 64 + c8;
    const float* p1 = p0 + 4 * 1024;
    f32x4 a0 = *(const f32x4*)p0, a1 = *(const f32x4*)(p0 + 4);
    f32x4 b0 = *(const f32x4*)p1, b1 = *(const f32x4*)(p1 + 4);
    f32x4 o0 = {(a0[0] + b0[0]) / dn, (a0[1] + b0[1]) / dn,
                (a0[2] + b0[2]) / dn, (a0[3] + b0[3]) / dn};
    f32x4 o1 = {(a1[0] + b1[0]) / dn, (a1[1] + b1[1]) / dn,
                (a1[2] + b1[2]) / dn, (a1[3] + b1[3]) / dn};
    float* op = &ctx[((size_t)b * SEQ + qbase + mm * 16 + row) * HIDDEN + h * 64 + c8];
    *(f32x4*)op = o0;
    *(f32x4*)(op + 4) = o1;
  }
}

// ---------------- launch ----------------
extern "C" void kernel_launch(void* const* d_in, const int* in_sizes, int n_in,
                              void* d_out, int out_size, void* d_ws, size_t ws_size,
                              hipStream_t stream) {
  const float* hidden = (const float*)d_in[0];
  const float* mask   = (const float*)d_in[1];
  const int*   wq  = (const int*)d_in[2];
  const float* wsq = (const float*)d_in[3];
  const float* bq  = (const float*)d_in[4];
  const int*   wk  = (const int*)d_in[5];
  const float* wsk = (const float*)d_in[6];
  const float* bk  = (const float*)d_in[7];
  const int*   wv  = (const int*)d_in[8];
  const float* wsv = (const float*)d_in[9];
  const float* bv  = (const float*)d_in[10];
  const int*   wo  = (const int*)d_in[11];
  const float* wso = (const float*)d_in[12];
  const float* bo  = (const float*)d_in[13];

  char* ws = (char*)d_ws;
  signed char*    pwq   = (signed char*)(ws + OFF_WQ);
  signed char*    pwk   = (signed char*)(ws + OFF_WK);
  signed char*    pwv   = (signed char*)(ws + OFF_WV);
  signed char*    pwo   = (signed char*)(ws + OFF_WO);
  signed char*    xq1   = (signed char*)(ws + OFF_XQ1);
  float*          sc1   = (float*)(ws + OFF_SC1);
  unsigned short* qhp   = (unsigned short*)(ws + OFF_QH);
  unsigned short* khp   = (unsigned short*)(ws + OFF_KH);
  unsigned short* vtp   = (unsigned short*)(ws + OFF_VT);
  float*          ctxp  = (float*)(ws + OFF_CTX);
  signed char*    xq2   = (signed char*)(ws + OFF_XQ2);
  float*          sc2   = (float*)(ws + OFF_SC2);

  prep_kernel<<<TOKENS + 2304, 256, 0, stream>>>(hidden, xq1, sc1,
                                                 wq, wk, wv, wo, pwq, pwk, pwv, pwo);
  qkv_gemm<<<dim3(32, 6, 3), 256, 0, stream>>>(xq1, sc1, pwq, pwk, pwv,
                                               wsq, wsk, wsv, bq, bk, bv,
                                               qhp, khp, vtp);
  attn_kernel<<<768, 512, 0, stream>>>(qhp, khp, vtp, mask, g_pla, ctxp);
  quant_kernel<<<TOKENS, 256, 0, stream>>>(ctxp, xq2, sc2);
  o_gemm<<<dim3(32, 6, 1), 256, 0, stream>>>(xq2, sc2, pwo, wso, bo, (float*)d_out);
}

// Round 15
// 93.035 us; speedup vs baseline: 2.4709x; 1.0384x over previous
//
#include <hip/hip_runtime.h>
#include <stdint.h>
#include <cmath>

#define TOKENS 4096
#define HIDDEN 768
#define NHEADS 12
#define SEQ    1024
#define NBH    48   // B*NHEADS

typedef int   int32x4 __attribute__((ext_vector_type(4)));
typedef float f32x4   __attribute__((ext_vector_type(4)));
typedef short short8  __attribute__((ext_vector_type(8)));

struct PlaCoeffs { float m[12]; float c[12]; };

// ---------------- workspace layout (bytes) ----------------
#define WBYTES   ((size_t)HIDDEN * HIDDEN)
#define OFF_WQ    ((size_t)256)
#define OFF_WK    (OFF_WQ + WBYTES)
#define OFF_WV    (OFF_WK + WBYTES)
#define OFF_WO    (OFF_WV + WBYTES)
#define OFF_XQ1   (OFF_WO + WBYTES)
#define OFF_SC1   (OFF_XQ1 + (size_t)TOKENS * HIDDEN)
#define OFF_QH    (OFF_SC1 + (size_t)TOKENS * 4)
#define HB        ((size_t)NBH * SEQ * 64 * 2)
#define OFF_KH    (OFF_QH + HB)
#define OFF_VT    (OFF_KH + HB)
#define OFF_CTX   (OFF_VT + HB)
#define OFF_XQ2   (OFF_CTX + (size_t)TOKENS * HIDDEN * 4)
#define OFF_SC2   (OFF_XQ2 + (size_t)TOKENS * HIDDEN)

__device__ __forceinline__ unsigned short f2bf(float f) {
  unsigned int u = __float_as_uint(f);
  u = (u + 0x7fffu + ((u >> 16) & 1u)) >> 16;
  return (unsigned short)u;
}

// packed RTNE f32x2 -> bf16x2 (low = a, high = b); bit-identical to f2bf per element
__device__ __forceinline__ unsigned int cvtpk_bf16(float a, float b) {
  unsigned int r;
  asm volatile("v_cvt_pk_bf16_f32 %0, %1, %2" : "=v"(r) : "v"(a), "v"(b));
  return r;
}

// ---------------- PLA coefficients: host-side, replicates np.polyfit fit ----------------
static PlaCoeffs compute_pla_coeffs() {
  PlaCoeffs out;
  const double step_e = 10.0 / 12.0;
  for (int i = 0; i < 12; i++) {
    double e0 = (double)i * step_e + (-10.0);
    double e1 = (i + 1 == 12) ? 0.0 : (double)(i + 1) * step_e + (-10.0);
    double n = 0.0, Sx = 0.0, Sy = 0.0, Sxy = 0.0, Sxx = 0.0;
    for (int j = 0; j <= 1000; j++) {
      double x = (j == 1000) ? 0.0 : (double)j * 0.01 + (-10.0);  // == np.linspace(-10,0,1001)
      if (x >= e0 && x <= e1) {
        double y = std::exp(x);
        n += 1.0; Sx += x; Sy += y; Sxy += x * y; Sxx += x * x;
      }
    }
    double det = n * Sxx - Sx * Sx;
    double m = (n * Sxy - Sx * Sy) / det;
    double c = (Sy - m * Sx) / n;
    out.m[i] = (float)m;
    out.c[i] = (float)c;
  }
  return out;
}
static const PlaCoeffs g_pla = compute_pla_coeffs();

// ---------------- fused: per-token quant (blocks 0..4095) + weight pack (4096..6399) ----
__global__ void prep_kernel(const float* __restrict__ x, signed char* __restrict__ xq,
                            float* __restrict__ sc,
                            const int* __restrict__ w0, const int* __restrict__ w1,
                            const int* __restrict__ w2, const int* __restrict__ w3,
                            signed char* __restrict__ o0, signed char* __restrict__ o1,
                            signed char* __restrict__ o2, signed char* __restrict__ o3) {
  int tid = threadIdx.x;
  if (blockIdx.x < TOKENS) {
    int t = blockIdx.x;
    const float* row = x + (size_t)t * HIDDEN;
    float v0 = row[tid], v1 = row[tid + 256], v2 = row[tid + 512];
    float am = fmaxf(fabsf(v0), fmaxf(fabsf(v1), fabsf(v2)));
#pragma unroll
    for (int m = 1; m < 64; m <<= 1) am = fmaxf(am, __shfl_xor(am, m, 64));
    __shared__ float red[4];
    if ((tid & 63) == 0) red[tid >> 6] = am;
    __syncthreads();
    float total = fmaxf(fmaxf(red[0], red[1]), fmaxf(red[2], red[3]));
    float s = total / 127.0f;
    if (s == 0.0f) s = 1.0f;
    float q0 = fminf(fmaxf(rintf(v0 / s), -128.0f), 127.0f);
    float q1 = fminf(fmaxf(rintf(v1 / s), -128.0f), 127.0f);
    float q2 = fminf(fmaxf(rintf(v2 / s), -128.0f), 127.0f);
    signed char* orow = xq + (size_t)t * HIDDEN;
    orow[tid]       = (signed char)(int)q0;
    orow[tid + 256] = (signed char)(int)q1;
    orow[tid + 512] = (signed char)(int)q2;
    if (tid == 0) sc[t] = s;
  } else {
    int p = blockIdx.x - TOKENS;
    int z = p / 576, px = p % 576;
    const int* src = z == 0 ? w0 : z == 1 ? w1 : z == 2 ? w2 : w3;
    signed char* dst = z == 0 ? o0 : z == 1 ? o1 : z == 2 ? o2 : o3;
    int idx = (px * 256 + tid) * 4;
    int32x4 v = *(const int32x4*)(src + idx);
    int packed = (v[0] & 255) | ((v[1] & 255) << 8) | ((v[2] & 255) << 16) | (v[3] << 24);
    *(int*)(dst + idx) = packed;
  }
}

// ---------------- per-token dynamic int8 quantization (for ctx) ----------------
__global__ void quant_kernel(const float* __restrict__ x, signed char* __restrict__ xq,
                             float* __restrict__ sc) {
  int t = blockIdx.x;
  int tid = threadIdx.x;
  const float* row = x + (size_t)t * HIDDEN;
  float v0 = row[tid], v1 = row[tid + 256], v2 = row[tid + 512];
  float am = fmaxf(fabsf(v0), fmaxf(fabsf(v1), fabsf(v2)));
#pragma unroll
  for (int m = 1; m < 64; m <<= 1) am = fmaxf(am, __shfl_xor(am, m, 64));
  __shared__ float red[4];
  if ((tid & 63) == 0) red[tid >> 6] = am;
  __syncthreads();
  float total = fmaxf(fmaxf(red[0], red[1]), fmaxf(red[2], red[3]));
  float s = total / 127.0f;
  if (s == 0.0f) s = 1.0f;
  float q0 = fminf(fmaxf(rintf(v0 / s), -128.0f), 127.0f);
  float q1 = fminf(fmaxf(rintf(v1 / s), -128.0f), 127.0f);
  float q2 = fminf(fmaxf(rintf(v2 / s), -128.0f), 127.0f);
  signed char* orow = xq + (size_t)t * HIDDEN;
  orow[tid]       = (signed char)(int)q0;
  orow[tid + 256] = (signed char)(int)q1;
  orow[tid + 512] = (signed char)(int)q2;
  if (tid == 0) sc[t] = s;
}

// ---------------- shared int8 GEMM mainloop: 128x128 tile, BK=128, LDS dbuf ------------
__device__ __forceinline__ void i8_mainloop(const signed char* __restrict__ Abase,
                                            const signed char* __restrict__ Bbase,
                                            char* As, char* Bs, int tid,
                                            int32x4 acc[4][4]) {
  int lane = tid & 63, w = tid >> 6;
  int lr = lane & 15, lg = lane >> 4;
  int wr = w >> 1, wc = w & 1;
  int laneoff = (lane >> 3) * HIDDEN + (((lane & 7) ^ (lane >> 3)) * 16);
  int rowblk = w * 32;

#pragma unroll
  for (int ii = 0; ii < 4; ii++) {
    const signed char* sa = Abase + (size_t)(rowblk + ii * 8) * HIDDEN + laneoff;
    const signed char* sb = Bbase + (size_t)(rowblk + ii * 8) * HIDDEN + laneoff;
    __builtin_amdgcn_global_load_lds(
        (const __attribute__((address_space(1))) void*)sa,
        (__attribute__((address_space(3))) void*)(As + (w * 4 + ii) * 1024), 16, 0, 0);
    __builtin_amdgcn_global_load_lds(
        (const __attribute__((address_space(1))) void*)sb,
        (__attribute__((address_space(3))) void*)(Bs + (w * 4 + ii) * 1024), 16, 0, 0);
  }
  __syncthreads();

  int buf = 0;
  for (int ks = 0; ks < 6; ks++) {
    if (ks < 5) {
      char* An = As + (buf ^ 1) * 16384;
      char* Bn = Bs + (buf ^ 1) * 16384;
#pragma unroll
      for (int ii = 0; ii < 4; ii++) {
        const signed char* sa =
            Abase + (size_t)(rowblk + ii * 8) * HIDDEN + (ks + 1) * 128 + laneoff;
        const signed char* sb =
            Bbase + (size_t)(rowblk + ii * 8) * HIDDEN + (ks + 1) * 128 + laneoff;
        __builtin_amdgcn_global_load_lds(
            (const __attribute__((address_space(1))) void*)sa,
            (__attribute__((address_space(3))) void*)(An + (w * 4 + ii) * 1024), 16, 0, 0);
        __builtin_amdgcn_global_load_lds(
            (const __attribute__((address_space(1))) void*)sb,
            (__attribute__((address_space(3))) void*)(Bn + (w * 4 + ii) * 1024), 16, 0, 0);
      }
    }
    const char* Ac = As + buf * 16384;
    const char* Bc = Bs + buf * 16384;
#pragma unroll
    for (int ksub = 0; ksub < 2; ksub++) {
      int32x4 af[4], bf[4];
      int cs = (ksub * 4 + lg) ^ (lr & 7);
#pragma unroll
      for (int i = 0; i < 4; i++)
        af[i] = *(const int32x4*)(Ac + (wr * 64 + i * 16 + lr) * 128 + cs * 16);
#pragma unroll
      for (int j = 0; j < 4; j++)
        bf[j] = *(const int32x4*)(Bc + (wc * 64 + j * 16 + lr) * 128 + cs * 16);
#pragma unroll
      for (int i = 0; i < 4; i++)
#pragma unroll
        for (int j = 0; j < 4; j++)
          acc[i][j] = __builtin_amdgcn_mfma_i32_16x16x64_i8(af[i], bf[j], acc[i][j], 0, 0, 0);
    }
    __syncthreads();
    buf ^= 1;
  }
}

// ---------------- QKV int8 MFMA GEMM (M=4096,N=768,K=768) ----------------
__launch_bounds__(256, 2)
__global__ void qkv_gemm(const signed char* __restrict__ xq, const float* __restrict__ isc,
                         const signed char* __restrict__ wq, const signed char* __restrict__ wk,
                         const signed char* __restrict__ wv,
                         const float* __restrict__ wsq, const float* __restrict__ wsk,
                         const float* __restrict__ wsv,
                         const float* __restrict__ bq, const float* __restrict__ bk,
                         const float* __restrict__ bv,
                         unsigned short* __restrict__ qh, unsigned short* __restrict__ kh,
                         unsigned short* __restrict__ vt) {
  __shared__ __align__(16) char As[2 * 16384];
  __shared__ __align__(16) char Bs[2 * 16384];
  int z = blockIdx.z;
  const signed char* w   = z == 0 ? wq  : z == 1 ? wk  : wv;
  const float*       wsc = z == 0 ? wsq : z == 1 ? wsk : wsv;
  const float*       bias= z == 0 ? bq  : z == 1 ? bk  : bv;
  unsigned short*    out = z == 0 ? qh  : z == 1 ? kh  : vt;

  int tid = threadIdx.x;
  int lane = tid & 63, wave = tid >> 6;
  int lr = lane & 15, lg = lane >> 4;
  int mbase0 = blockIdx.x * 128;
  int mbase = mbase0 + (wave >> 1) * 64;
  int nbase = blockIdx.y * 128 + (wave & 1) * 64;

  int32x4 acc[4][4];
#pragma unroll
  for (int i = 0; i < 4; i++)
#pragma unroll
    for (int j = 0; j < 4; j++) acc[i][j] = (int32x4){0, 0, 0, 0};

  i8_mainloop(xq + (size_t)mbase0 * HIDDEN,
              w + (size_t)blockIdx.y * 128 * HIDDEN, As, Bs, tid, acc);

  if (z < 2) {
#pragma unroll
    for (int j = 0; j < 4; j++) {
      int col = nbase + j * 16 + lr;
      float wsv_ = wsc[col], bv_ = bias[col];
      int h = col >> 6, d = col & 63;
#pragma unroll
      for (int i = 0; i < 4; i++) {
#pragma unroll
        for (int r = 0; r < 4; r++) {
          int trow = mbase + i * 16 + lg * 4 + r;
          float v = (float)acc[i][j][r] * wsv_ * isc[trow] + bv_;
          int bb = trow >> 10, ss = trow & 1023;
          out[(((size_t)(bb * NHEADS + h)) * SEQ + ss) * 64 + d] = f2bf(v);
        }
      }
    }
  } else {
    // V^T: dequant -> bf16 -> swizzled LDS transpose -> coalesced 16B stores
    unsigned short* T = (unsigned short*)As;
#pragma unroll
    for (int j = 0; j < 4; j++) {
      int colc = (wave & 1) * 64 + j * 16 + lr;
      int gcol = blockIdx.y * 128 + colc;
      float wsv_ = wsc[gcol], bv_ = bias[gcol];
      int rlb = (wave >> 1) * 64 + lg * 4;
#pragma unroll
      for (int i = 0; i < 4; i++) {
        int rl = rlb + i * 16;
        float v0 = (float)acc[i][j][0] * wsv_ * isc[mbase0 + rl + 0] + bv_;
        float v1 = (float)acc[i][j][1] * wsv_ * isc[mbase0 + rl + 1] + bv_;
        float v2 = (float)acc[i][j][2] * wsv_ * isc[mbase0 + rl + 2] + bv_;
        float v3 = (float)acc[i][j][3] * wsv_ * isc[mbase0 + rl + 3] + bv_;
        int oct = (rl >> 3) ^ (colc & 7);
        unsigned short* dst = T + colc * 128 + (oct << 3) + (rl & 7);
        *(unsigned int*)(dst)     = cvtpk_bf16(v0, v1);
        *(unsigned int*)(dst + 2) = cvtpk_bf16(v2, v3);
      }
    }
    __syncthreads();
    int bb = mbase0 >> 10, ssb = mbase0 & 1023;
    int o = tid & 15, cb = (tid >> 4) * 8;
#pragma unroll
    for (int j = 0; j < 8; j++) {
      int colc = cb + j;
      int gcol = blockIdx.y * 128 + colc;
      int hh = gcol >> 6, dd = gcol & 63;
      unsigned short* g = out + (((size_t)(bb * NHEADS + hh)) * 64 + dd) * SEQ + ssb + o * 8;
      *(short8*)g = *(const short8*)(T + colc * 128 + ((o ^ (colc & 7)) << 3));
    }
  }
}

// ---------------- O-proj int8 MFMA GEMM -> fp32 d_out ----------------
__launch_bounds__(256, 2)
__global__ void o_gemm(const signed char* __restrict__ xq, const float* __restrict__ isc,
                       const signed char* __restrict__ w, const float* __restrict__ wsc,
                       const float* __restrict__ bias, float* __restrict__ out) {
  __shared__ __align__(16) char As[2 * 16384];
  __shared__ __align__(16) char Bs[2 * 16384];
  int tid = threadIdx.x;
  int lane = tid & 63, wave = tid >> 6;
  int lr = lane & 15, lg = lane >> 4;
  int mbase = blockIdx.x * 128 + (wave >> 1) * 64;
  int nbase = blockIdx.y * 128 + (wave & 1) * 64;

  int32x4 acc[4][4];
#pragma unroll
  for (int i = 0; i < 4; i++)
#pragma unroll
    for (int j = 0; j < 4; j++) acc[i][j] = (int32x4){0, 0, 0, 0};

  i8_mainloop(xq + (size_t)blockIdx.x * 128 * HIDDEN,
              w + (size_t)blockIdx.y * 128 * HIDDEN, As, Bs, tid, acc);

#pragma unroll
  for (int j = 0; j < 4; j++) {
    int col = nbase + j * 16 + lr;
    float wsv_ = wsc[col], bv_ = bias[col];
#pragma unroll
    for (int i = 0; i < 4; i++) {
#pragma unroll
      for (int r = 0; r < 4; r++) {
        int trow = mbase + i * 16 + lg * 4 + r;
        float v = (float)acc[i][j][r] * wsv_ * isc[trow] + bv_;
        out[(size_t)trow * HIDDEN + col] = v;
      }
    }
  }
}

// ---------------- attention: 64 q-rows/block, double-buffered 64-col chunks ------------
// Proven best configuration (53.9 us; reproduced R8 and R11): 2-pass PLA, dbuf K/V
// staging, 1 barrier/chunk, LDS PLA table, cvt_pk P-conversion, non-atomic tail combine.
// 51200 B LDS, 40 VGPR, 2 blk/CU (50% occupancy).
__launch_bounds__(512, 6)
__global__ void attn_kernel(const unsigned short* __restrict__ qh,
                            const unsigned short* __restrict__ kgl,
                            const unsigned short* __restrict__ vt,
                            const float* __restrict__ mask,
                            const PlaCoeffs cf,
                            float* __restrict__ ctx) {
  __shared__ __align__(16) char smem[49152];
  unsigned short* kbuf = (unsigned short*)smem;            // [2][4096] ushort
  unsigned short* vbuf = (unsigned short*)(smem + 16384);  // [2][4096]
  unsigned short* plds = (unsigned short*)(smem + 32768);  // [8][1024] per-wave P
  float* parts = (float*)smem;                             // [8][16][64] post-loop alias
  __shared__ float rmaxp[8][16], rmaxv[4][16], rsump[8][16], rsumv[4][16];
  __shared__ float2 lmc[12];

  int tid = threadIdx.x;
  int lane = tid & 63, w = tid >> 6;
  int lr = lane & 15, lg = lane >> 4;
  int m = w & 3, kh2 = w >> 2;

  if (tid < 12) lmc[tid] = make_float2(cf.m[tid], cf.c[tid]);

  // bijective XCD swizzle: 768 = 8 XCD x 96; 6 whole heads per XCD
  int nb = (blockIdx.x & 7) * 96 + (blockIdx.x >> 3);
  int bh = nb >> 4, qt = nb & 15;
  int b = bh / NHEADS, h = bh % NHEADS;
  int qbase = qt * 64;

  const unsigned short* qp     = qh + ((size_t)bh * SEQ + qbase + m * 16) * 64;
  const unsigned short* khead  = kgl + (size_t)bh * SEQ * 64;
  const unsigned short* vthead = vt + (size_t)bh * 64 * SEQ;
  const float* mrow = mask + b * SEQ;

  short8 qa0 = *(const short8*)(qp + (size_t)lr * 64 + lg * 8);
  short8 qa1 = *(const short8*)(qp + (size_t)lr * 64 + 32 + lg * 8);

  int sr = tid >> 3, sd = (tid & 7) * 8;
  int sidx = sr * 64 + (sd ^ ((sr & 7) << 3));
  const unsigned short* kgp = khead + (size_t)sr * 64 + sd;    // + c*4096
  const unsigned short* vgp = vthead + (size_t)sr * 1024 + sd; // + c*64

  // ---- phase A: row max (K dbuf-staged, 1 barrier/chunk) ----
  float rm[4] = {-3.0e38f, -3.0e38f, -3.0e38f, -3.0e38f};
  short8 stk = *(const short8*)kgp;
  for (int c = 0; c < 16; c++) {
    unsigned short* kb = kbuf + (c & 1) * 4096;
    *(short8*)(kb + sidx) = stk;
    if (c < 15) stk = *(const short8*)(kgp + (size_t)(c + 1) * 4096);
    __syncthreads();
#pragma unroll
    for (int kt = 0; kt < 2; kt++) {
      int krow = kh2 * 32 + kt * 16 + lr;
      const unsigned short* kbp = kb + krow * 64;
      int sw = (krow & 7) << 3;
      short8 k0 = *(const short8*)(kbp + ((lg * 8) ^ sw));
      short8 k1 = *(const short8*)(kbp + ((32 + lg * 8) ^ sw));
      f32x4 a = {0.f, 0.f, 0.f, 0.f};
      __builtin_amdgcn_s_setprio(1);
      a = __builtin_amdgcn_mfma_f32_16x16x32_bf16(qa0, k0, a, 0, 0, 0);
      a = __builtin_amdgcn_mfma_f32_16x16x32_bf16(qa1, k1, a, 0, 0, 0);
      __builtin_amdgcn_s_setprio(0);
      float mk = mrow[c * 64 + krow];
#pragma unroll
      for (int r = 0; r < 4; r++) rm[r] = fmaxf(rm[r], fmaf(a[r], 0.125f, mk));
    }
  }
#pragma unroll
  for (int r = 0; r < 4; r++) {
#pragma unroll
    for (int msk = 1; msk < 16; msk <<= 1) rm[r] = fmaxf(rm[r], __shfl_xor(rm[r], msk, 64));
  }
  if (lr == 0) {
#pragma unroll
    for (int r = 0; r < 4; r++) rmaxp[w][lg * 4 + r] = rm[r];
  }
  __syncthreads();
  if (tid < 64) {
    int mm = tid >> 4, row = tid & 15;
    rmaxv[mm][row] = fmaxf(rmaxp[mm][row], rmaxp[mm + 4][row]);
  }
  __syncthreads();

  // ---- phase B: QK -> PLA -> PV (K+V dbuf-staged, 1 barrier/chunk) ----
  float rmx[4], rs[4];
#pragma unroll
  for (int r = 0; r < 4; r++) { rmx[r] = rmaxv[m][lg * 4 + r]; rs[r] = 0.f; }
  f32x4 pacc[4];
#pragma unroll
  for (int n = 0; n < 4; n++) pacc[n] = (f32x4){0.f, 0.f, 0.f, 0.f};
  unsigned short* pw = plds + w * 1024;  // private 16 rows x 64 ushorts

  short8 stk2 = *(const short8*)kgp;
  short8 stv  = *(const short8*)vgp;
  for (int c = 0; c < 16; c++) {
    unsigned short* kb = kbuf + (c & 1) * 4096;
    unsigned short* vb = vbuf + (c & 1) * 4096;
    *(short8*)(kb + sidx) = stk2;
    *(short8*)(vb + sidx) = stv;
    if (c < 15) {
      stk2 = *(const short8*)(kgp + (size_t)(c + 1) * 4096);
      stv  = *(const short8*)(vgp + (c + 1) * 64);
    }
    __syncthreads();
#pragma unroll
    for (int kt = 0; kt < 2; kt++) {
      int krow = kh2 * 32 + kt * 16 + lr;
      const unsigned short* kbp = kb + krow * 64;
      int sw = (krow & 7) << 3;
      short8 k0 = *(const short8*)(kbp + ((lg * 8) ^ sw));
      short8 k1 = *(const short8*)(kbp + ((32 + lg * 8) ^ sw));
      f32x4 a = {0.f, 0.f, 0.f, 0.f};
      __builtin_amdgcn_s_setprio(1);
      a = __builtin_amdgcn_mfma_f32_16x16x32_bf16(qa0, k0, a, 0, 0, 0);
      a = __builtin_amdgcn_mfma_f32_16x16x32_bf16(qa1, k1, a, 0, 0, 0);
      __builtin_amdgcn_s_setprio(0);
      float mk = mrow[c * 64 + krow];
      float p[4];
#pragma unroll
      for (int r = 0; r < 4; r++) {
        float x = fmaf(a[r], 0.125f, mk) - rmx[r];
        x = fminf(fmaxf(x, -10.f), 0.f);             // v_med3_f32
        int ii = (int)fmaf(x, 1.2f, 12.0f);
        ii = ii > 10 ? 10 : ii;
        float2 mc = lmc[ii];
        p[r] = fmaf(mc.x, x, mc.y);
        rs[r] += p[r];
      }
      unsigned int pk01 = cvtpk_bf16(p[0], p[1]);
      unsigned int pk23 = cvtpk_bf16(p[2], p[3]);
      int colw = kt * 16 + lr;
      int r0 = lg * 4;
      pw[(r0 + 0) * 64 + (colw ^ (((r0 + 0) & 7) << 3))] = (unsigned short)pk01;
      pw[(r0 + 1) * 64 + (colw ^ (((r0 + 1) & 7) << 3))] = (unsigned short)(pk01 >> 16);
      pw[(r0 + 2) * 64 + (colw ^ (((r0 + 2) & 7) << 3))] = (unsigned short)pk23;
      pw[(r0 + 3) * 64 + (colw ^ (((r0 + 3) & 7) << 3))] = (unsigned short)(pk23 >> 16);
    }
    short8 pa = *(const short8*)(pw + lr * 64 + ((lg * 8) ^ ((lr & 7) << 3)));
    __builtin_amdgcn_s_setprio(1);
#pragma unroll
    for (int n = 0; n < 4; n++) {
      int d = n * 16 + lr;
      short8 vv = *(const short8*)(vb + d * 64 + ((kh2 * 32 + lg * 8) ^ ((d & 7) << 3)));
      pacc[n] = __builtin_amdgcn_mfma_f32_16x16x32_bf16(pa, vv, pacc[n], 0, 0, 0);
    }
    __builtin_amdgcn_s_setprio(0);
  }

  // ---- tail: row sums + non-atomic PV combine (parts aliased over stage bufs) ----
#pragma unroll
  for (int r = 0; r < 4; r++) {
#pragma unroll
    for (int msk = 1; msk < 16; msk <<= 1) rs[r] += __shfl_xor(rs[r], msk, 64);
  }
  if (lr == 0) {
#pragma unroll
    for (int r = 0; r < 4; r++) rsump[w][lg * 4 + r] = rs[r];
  }
  __syncthreads();  // all PV reads done; kbuf/vbuf free, rsump visible
  {
    float* pslice = parts + w * 1024;  // [16][64]
#pragma unroll
    for (int n = 0; n < 4; n++)
#pragma unroll
      for (int r = 0; r < 4; r++)
        pslice[(lg * 4 + r) * 64 + n * 16 + lr] = pacc[n][r];
  }
  if (tid < 64) {
    int mm = tid >> 4, row = tid & 15;
    rsumv[mm][row] = rsump[mm][row] + rsump[mm + 4][row];
  }
  __syncthreads();

  // epilogue: out[mm*16+row][c8..c8+7] = (parts[mm] + parts[mm+4]) / denom
  {
    int mm = tid >> 7, row = (tid >> 3) & 15, c8 = (tid & 7) * 8;
    float dn = rsumv[mm][row] + 1e-9f;
    const float* p0 = parts + (mm * 16 + row) * 64 + c8;
    const float* p1 = p0 + 4 * 1024;
    f32x4 a0 = *(const f32x4*)p0, a1 = *(const f32x4*)(p0 + 4);
    f32x4 b0 = *(const f32x4*)p1, b1 = *(const f32x4*)(p1 + 4);
    f32x4 o0 = {(a0[0] + b0[0]) / dn, (a0[1] + b0[1]) / dn,
                (a0[2] + b0[2]) / dn, (a0[3] + b0[3]) / dn};
    f32x4 o1 = {(a1[0] + b1[0]) / dn, (a1[1] + b1[1]) / dn,
                (a1[2] + b1[2]) / dn, (a1[3] + b1[3]) / dn};
    float* op = &ctx[((size_t)b * SEQ + qbase + mm * 16 + row) * HIDDEN + h * 64 + c8];
    *(f32x4*)op = o0;
    *(f32x4*)(op + 4) = o1;
  }
}

// ---------------- launch ----------------
extern "C" void kernel_launch(void* const* d_in, const int* in_sizes, int n_in,
                              void* d_out, int out_size, void* d_ws, size_t ws_size,
                              hipStream_t stream) {
  const float* hidden = (const float*)d_in[0];
  const float* mask   = (const float*)d_in[1];
  const int*   wq  = (const int*)d_in[2];
  const float* wsq = (const float*)d_in[3];
  const float* bq  = (const float*)d_in[4];
  const int*   wk  = (const int*)d_in[5];
  const float* wsk = (const float*)d_in[6];
  const float* bk  = (const float*)d_in[7];
  const int*   wv  = (const int*)d_in[8];
  const float* wsv = (const float*)d_in[9];
  const float* bv  = (const float*)d_in[10];
  const int*   wo  = (const int*)d_in[11];
  const float* wso = (const float*)d_in[12];
  const float* bo  = (const float*)d_in[13];

  char* ws = (char*)d_ws;
  signed char*    pwq   = (signed char*)(ws + OFF_WQ);
  signed char*    pwk   = (signed char*)(ws + OFF_WK);
  signed char*    pwv   = (signed char*)(ws + OFF_WV);
  signed char*    pwo   = (signed char*)(ws + OFF_WO);
  signed char*    xq1   = (signed char*)(ws + OFF_XQ1);
  float*          sc1   = (float*)(ws + OFF_SC1);
  unsigned short* qhp   = (unsigned short*)(ws + OFF_QH);
  unsigned short* khp   = (unsigned short*)(ws + OFF_KH);
  unsigned short* vtp   = (unsigned short*)(ws + OFF_VT);
  float*          ctxp  = (float*)(ws + OFF_CTX);
  signed char*    xq2   = (signed char*)(ws + OFF_XQ2);
  float*          sc2   = (float*)(ws + OFF_SC2);

  prep_kernel<<<TOKENS + 2304, 256, 0, stream>>>(hidden, xq1, sc1,
                                                 wq, wk, wv, wo, pwq, pwk, pwv, pwo);
  qkv_gemm<<<dim3(32, 6, 3), 256, 0, stream>>>(xq1, sc1, pwq, pwk, pwv,
                                               wsq, wsk, wsv, bq, bk, bv,
                                               qhp, khp, vtp);
  attn_kernel<<<768, 512, 0, stream>>>(qhp, khp, vtp, mask, g_pla, ctxp);
  quant_kernel<<<TOKENS, 256, 0, stream>>>(ctxp, xq2, sc2);
  o_gemm<<<dim3(32, 6, 1), 256, 0, stream>>>(xq2, sc2, pwo, wso, bo, (float*)d_out);
}